// Round 3
// baseline (63.661 us; speedup 1.0000x reference)
//
#include <hip/hip_runtime.h>

#define NUM_CENTERS 16

typedef float vfloat4 __attribute__((ext_vector_type(4)));

__device__ __forceinline__ float nearest_center(float v, const float* __restrict__ c) {
    // argmin over |v - c[i]|, first index wins ties (strict <), matching jnp.argmin
    float best_d   = fabsf(v - c[0]);
    float best_val = c[0];
#pragma unroll
    for (int i = 1; i < NUM_CENTERS; ++i) {
        float d = fabsf(v - c[i]);
        bool lt = d < best_d;
        best_d   = lt ? d : best_d;
        best_val = lt ? c[i] : best_val;
    }
    return best_val;
}

__device__ __forceinline__ vfloat4 nearest4(vfloat4 v, const float* __restrict__ c) {
    vfloat4 r;
    r.x = nearest_center(v.x, c);
    r.y = nearest_center(v.y, c);
    r.z = nearest_center(v.z, c);
    r.w = nearest_center(v.w, c);
    return r;
}

__global__ __launch_bounds__(256) void nearest_center_kernel(
    const vfloat4* __restrict__ x,
    const float* __restrict__ centers,
    vfloat4* __restrict__ out,
    int n4)  // number of vfloat4 groups
{
    // Centers: wave-uniform addresses -> scalar (s_load) broadcast into SGPRs.
    float c[NUM_CENTERS];
#pragma unroll
    for (int i = 0; i < NUM_CENTERS; ++i) c[i] = centers[i];

    int t      = blockIdx.x * blockDim.x + threadIdx.x;
    int stride = gridDim.x * blockDim.x;   // = n4/2 when launched as below
    int i0 = t;
    int i1 = t + stride;

    // Issue both streaming loads before any compute (2 outstanding dwordx4).
    if (i1 < n4) {
        vfloat4 a = __builtin_nontemporal_load(&x[i0]);
        vfloat4 b = __builtin_nontemporal_load(&x[i1]);
        vfloat4 ra = nearest4(a, c);
        vfloat4 rb = nearest4(b, c);
        __builtin_nontemporal_store(ra, &out[i0]);
        __builtin_nontemporal_store(rb, &out[i1]);
    } else if (i0 < n4) {
        vfloat4 a = __builtin_nontemporal_load(&x[i0]);
        vfloat4 ra = nearest4(a, c);
        __builtin_nontemporal_store(ra, &out[i0]);
    }
}

extern "C" void kernel_launch(void* const* d_in, const int* in_sizes, int n_in,
                              void* d_out, int out_size, void* d_ws, size_t ws_size,
                              hipStream_t stream) {
    const vfloat4* x     = (const vfloat4*)d_in[0];  // (8,64,64,64) fp32
    const float* centers = (const float*)d_in[1];    // (16,) fp32
    vfloat4* out         = (vfloat4*)d_out;

    int n  = in_sizes[0];        // 2,097,152
    int n4 = n / 4;              // 524,288 vfloat4 groups

    const int block = 256;
    const int elems_per_thread4 = 2;                       // 2 vfloat4 per thread
    int grid = (n4 + block * elems_per_thread4 - 1) / (block * elems_per_thread4);  // 1024
    nearest_center_kernel<<<grid, block, 0, stream>>>(x, centers, out, n4);
}